// Round 9
// baseline (13606.366 us; speedup 1.0000x reference)
//
#include <hip/hip_runtime.h>
#include <hip/hip_cooperative_groups.h>

namespace cg = cooperative_groups;

#define NN 100000
#define NE 1600000
#define FIN 128
#define HID 64
#define HEADS 8
#define KORD 14
#define NGRAPHS 128
#define NCLASSES 10
#define GRIDC 1536

static inline size_t align256(size_t x) { return (x + 255) & ~(size_t)255; }

// round-to-nearest-even f32 -> bf16 (as uint16 in low bits)
__device__ __forceinline__ unsigned bfr(float x) {
    unsigned u = __float_as_uint(x);
    return (u + 0x7fffu + ((u >> 16) & 1u)) >> 16;
}
__device__ __forceinline__ unsigned bfpack(float lo, float hi) {
    return bfr(lo) | (bfr(hi) << 16);
}
__device__ __forceinline__ float bflo(unsigned u) { return __uint_as_float(u << 16); }
__device__ __forceinline__ float bfhi(unsigned u) { return __uint_as_float(u & 0xffff0000u); }

// ---------------- setup kernels ----------------

__global__ void k_deg(const int* __restrict__ row, int* __restrict__ deg, int ne) {
    int e = blockIdx.x * 256 + threadIdx.x;
    if (e < ne) atomicAdd(&deg[row[e]], 1);
}

// dinv = rsqrt(max(deg,1)); d2 = 1/max(deg,1); rdinv = sqrt(max(deg,1))
__global__ void k_dinv(const int* __restrict__ deg, float* __restrict__ dinv,
                       float* __restrict__ d2, float* __restrict__ rdinv, int n) {
    int i = blockIdx.x * 256 + threadIdx.x;
    if (i < n) {
        float d = (float)deg[i];
        if (d < 1.f) d = 1.f;
        dinv[i] = rsqrtf(d);
        d2[i] = 1.f / d;
        rdinv[i] = sqrtf(d);
    }
}

// exclusive scan phase 1: per-block scan of PADDED degrees ((deg+7)&~7)
__global__ void k_scan1(const int* __restrict__ deg, int* __restrict__ rowptr,
                        int* __restrict__ bsum, int n) {
    __shared__ int s[256];
    int t = threadIdx.x;
    int i = blockIdx.x * 256 + t;
    int v = (i < n) ? ((deg[i] + 7) & ~7) : 0;
    s[t] = v;
    __syncthreads();
    for (int off = 1; off < 256; off <<= 1) {
        int add = (t >= off) ? s[t - off] : 0;
        __syncthreads();
        s[t] += add;
        __syncthreads();
    }
    if (i < n) rowptr[i] = s[t] - v;  // exclusive within block
    if (t == 255) bsum[blockIdx.x] = s[255];
}

// phase 2: single-block exclusive scan of block sums (nb <= 1024)
__global__ void k_scan2(int* __restrict__ bsum, int nb) {
    __shared__ int s[1024];
    int t = threadIdx.x;
    int v = (t < nb) ? bsum[t] : 0;
    s[t] = v;
    __syncthreads();
    for (int off = 1; off < 1024; off <<= 1) {
        int add = (t >= off) ? s[t - off] : 0;
        __syncthreads();
        s[t] += add;
        __syncthreads();
    }
    if (t < nb) bsum[t] = s[t] - v;  // exclusive
}

// phase 3: add block offsets; init cursor; write rowptr[n] (total padded edges)
__global__ void k_scan3(int* __restrict__ rowptr, int* __restrict__ cursor,
                        const int* __restrict__ bsum, const int* __restrict__ deg, int n) {
    int i = blockIdx.x * 256 + threadIdx.x;
    if (i < n) {
        int v = rowptr[i] + bsum[i >> 8];
        rowptr[i] = v;
        cursor[i] = v;
        if (i == n - 1) rowptr[n] = v + ((deg[i] + 7) & ~7);
    }
}

// pre-fill ccol with the zero-row index n (pad slots read row n == 0)
__global__ void k_filln(int* __restrict__ ccol, int npad, int n) {
    int i = blockIdx.x * 256 + threadIdx.x;
    if (i < npad) ccol[i] = n;
}

// fill CSR cols (weights are implicit in S-space)
__global__ void k_fill(const int* __restrict__ row, const int* __restrict__ col,
                       int* __restrict__ cursor, int* __restrict__ ccol, int ne) {
    int e = blockIdx.x * 256 + threadIdx.x;
    if (e >= ne) return;
    int pos = atomicAdd(&cursor[row[e]], 1);
    ccol[pos] = col[e];
}

// zero the pad row (row n) of all 7 slabs (each slab = (n+1) x 32 dwords)
__global__ void k_zrow(unsigned* __restrict__ slabs, int n) {
    int t = threadIdx.x;
    if (t >= 7 * 32) return;
    int sp = t >> 5;  // slab 0..6
    int q = t & 31;
    slabs[(size_t)sp * (size_t)(n + 1) * 32 + (size_t)n * 32 + q] = 0;
}

// coeff[l][k] = mean over heads of theta[l][h][k]
__global__ void k_coeff(const float* __restrict__ th1, const float* __restrict__ ths,
                        float* __restrict__ coeff) {
    int i = threadIdx.x;
    if (i >= 3 * KORD) return;
    int l = i / KORD, k = i % KORD;
    const float* t = (l == 0) ? th1 : ths + (l - 1) * HEADS * KORD;
    float s = 0.f;
    for (int h = 0; h < HEADS; ++h) s += t[h * KORD + k];
    coeff[i] = s * (1.f / HEADS);
}

// ---------------- main compute kernels ----------------

// S0 = dinv * (h @ W), written as bf16 [n][64] (= [n][32] dwords) slab.
template <int F>
__global__ __launch_bounds__(256) void k_gemm(const float* __restrict__ h,
                                              const float* __restrict__ W,
                                              unsigned* __restrict__ slab0,
                                              const float* __restrict__ dinv, int n) {
    __shared__ __align__(16) float Wl[F * 64];
    __shared__ float hl[64][F + 1];
    int tid = threadIdx.x;
    int row0 = blockIdx.x * 64;
    int nrows = n - row0;
    if (nrows > 64) nrows = 64;

    for (int i = tid; i < F * 64; i += 256) Wl[i] = W[i];
    for (int i = tid; i < nrows * F; i += 256) hl[i / F][i % F] = h[(size_t)row0 * F + i];
    __syncthreads();

    int rq = tid >> 4;
    int c0 = (tid & 15) * 4;
    float4 acc0 = {0, 0, 0, 0}, acc1 = {0, 0, 0, 0}, acc2 = {0, 0, 0, 0}, acc3 = {0, 0, 0, 0};
#pragma unroll 4
    for (int f = 0; f < F; ++f) {
        const float4 wv = *(const float4*)&Wl[f * 64 + c0];
        float h0 = hl[rq * 4 + 0][f];
        float h1 = hl[rq * 4 + 1][f];
        float h2 = hl[rq * 4 + 2][f];
        float h3 = hl[rq * 4 + 3][f];
        acc0.x = fmaf(h0, wv.x, acc0.x); acc0.y = fmaf(h0, wv.y, acc0.y);
        acc0.z = fmaf(h0, wv.z, acc0.z); acc0.w = fmaf(h0, wv.w, acc0.w);
        acc1.x = fmaf(h1, wv.x, acc1.x); acc1.y = fmaf(h1, wv.y, acc1.y);
        acc1.z = fmaf(h1, wv.z, acc1.z); acc1.w = fmaf(h1, wv.w, acc1.w);
        acc2.x = fmaf(h2, wv.x, acc2.x); acc2.y = fmaf(h2, wv.y, acc2.y);
        acc2.z = fmaf(h2, wv.z, acc2.z); acc2.w = fmaf(h2, wv.w, acc2.w);
        acc3.x = fmaf(h3, wv.x, acc3.x); acc3.y = fmaf(h3, wv.y, acc3.y);
        acc3.z = fmaf(h3, wv.z, acc3.z); acc3.w = fmaf(h3, wv.w, acc3.w);
    }
    int rem = nrows - rq * 4;
    float4 accs[4] = {acc0, acc1, acc2, acc3};
    int qd = c0 >> 1;
#pragma unroll
    for (int r = 0; r < 4; ++r) {
        if (r < rem) {
            int row = row0 + rq * 4 + r;
            float dv = dinv[row];
            uint2 p;
            p.x = bfpack(accs[r].x * dv, accs[r].y * dv);
            p.y = bfpack(accs[r].z * dv, accs[r].w * dv);
            *(uint2*)(slab0 + (size_t)row * 32 + qd) = p;
        }
    }
}

// Cooperative persistent layer kernel: 13 Chebyshev steps with grid.sync between,
// acc Σ c_k S_k kept in LDS f32, 2-slab ping-pong (prev = dst before overwrite).
// Final: H = relu(rdinv * acc + bias).
__global__ __launch_bounds__(256, 6) void k_layer(const int* __restrict__ rowptr,
                                                  const int* __restrict__ ccol,
                                                  unsigned* __restrict__ slabA,
                                                  unsigned* __restrict__ slabB,
                                                  const float* __restrict__ d2arr,
                                                  const float* __restrict__ rdinv,
                                                  const float* __restrict__ cf,
                                                  const float* __restrict__ bias,
                                                  float* __restrict__ H, int n, int R) {
    cg::grid_group gg = cg::this_grid();
    extern __shared__ float accL[];  // [R][64] f32
    int wave = threadIdx.x >> 6;
    int lane = threadIdx.x & 63;
    bool hi = lane >= 32;
    int fl = lane & 31;
    int r0 = blockIdx.x * R;

    // acc = c0 * S0(own rows), S0 from slabA (gemm output)
    float c0 = cf[0];
    for (int local = wave; local < R; local += 4) {
        int r = r0 + local;
        if (r >= n) break;
        if (!hi) {
            unsigned u = slabA[(size_t)r * 32 + fl];
            accL[local * 64 + fl * 2]     = c0 * bflo(u);
            accL[local * 64 + fl * 2 + 1] = c0 * bfhi(u);
        }
    }

    unsigned* src = slabA;
    unsigned* dst = slabB;
    for (int k = 1; k <= 13; ++k) {
        float ck = cf[k];
        for (int local = wave; local < R; local += 4) {
            int r = r0 + local;
            if (r >= n) break;
            int rr = __builtin_amdgcn_readfirstlane(r);
            const int e0 = __builtin_amdgcn_readfirstlane(rowptr[rr]);
            const int e1 = __builtin_amdgcn_readfirstlane(rowptr[rr + 1]);
            float a0 = 0.f, a1 = 0.f;
            for (int e = e0; e < e1; e += 8) {
                const int4* q = (const int4*)(ccol + e);
                int4 q0 = q[0];
                int4 q1 = q[1];
                int cA = hi ? q1.x : q0.x;
                int cB = hi ? q1.y : q0.y;
                int cC = hi ? q1.z : q0.z;
                int cD = hi ? q1.w : q0.w;
                unsigned uA = src[(size_t)cA * 32 + fl];
                unsigned uB = src[(size_t)cB * 32 + fl];
                unsigned uC = src[(size_t)cC * 32 + fl];
                unsigned uD = src[(size_t)cD * 32 + fl];
                a0 += bflo(uA); a1 += bfhi(uA);
                a0 += bflo(uB); a1 += bfhi(uB);
                a0 += bflo(uC); a1 += bfhi(uC);
                a0 += bflo(uD); a1 += bfhi(uD);
            }
            a0 += __shfl_xor(a0, 32, 64);
            a1 += __shfl_xor(a1, 32, 64);
            if (!hi) {
                float d2v = d2arr[rr];
                size_t di = (size_t)rr * 32 + fl;
                float sx, sy;
                if (k == 1) {
                    sx = -d2v * a0;
                    sy = -d2v * a1;
                } else {
                    unsigned pu = dst[di];  // S_{k-2} (own row, about to be overwritten)
                    sx = fmaf(-2.f * d2v, a0, -bflo(pu));
                    sy = fmaf(-2.f * d2v, a1, -bfhi(pu));
                }
                accL[local * 64 + fl * 2]     += ck * sx;
                accL[local * 64 + fl * 2 + 1] += ck * sy;
                dst[di] = bfpack(sx, sy);
            }
        }
        unsigned* t = src; src = dst; dst = t;
        if (k < 13) {
            __threadfence();
            gg.sync();
        }
    }

    for (int local = wave; local < R; local += 4) {
        int r = r0 + local;
        if (r >= n) break;
        if (!hi) {
            float rd = rdinv[r];
            float vx = fmaf(accL[local * 64 + fl * 2], rd, bias[fl * 2]);
            float vy = fmaf(accL[local * 64 + fl * 2 + 1], rd, bias[fl * 2 + 1]);
            vx = vx > 0.f ? vx : 0.f;
            vy = vy > 0.f ? vy : 0.f;
            *(float2*)(H + (size_t)r * 64 + fl * 2) = make_float2(vx, vy);
        }
    }
}

// ---- fallback (R8) kernels ----

template <bool FIRST>
__global__ __launch_bounds__(256) void k_prop(const int* __restrict__ rowptr,
                                              const int* __restrict__ ccol,
                                              const unsigned* __restrict__ src,
                                              const unsigned* __restrict__ prev,
                                              unsigned* __restrict__ dst,
                                              const float* __restrict__ d2arr, int n) {
    int r = (blockIdx.x * 256 + threadIdx.x) >> 6;
    int lane = threadIdx.x & 63;
    if (r >= n) return;
    r = __builtin_amdgcn_readfirstlane(r);
    const int e0 = __builtin_amdgcn_readfirstlane(rowptr[r]);
    const int e1 = __builtin_amdgcn_readfirstlane(rowptr[r + 1]);
    const bool hi = lane >= 32;
    const int fl = lane & 31;
    float a0 = 0.f, a1 = 0.f;
    for (int e = e0; e < e1; e += 8) {
        const int4* q = (const int4*)(ccol + e);
        int4 q0 = q[0];
        int4 q1 = q[1];
        int cA = hi ? q1.x : q0.x;
        int cB = hi ? q1.y : q0.y;
        int cC = hi ? q1.z : q0.z;
        int cD = hi ? q1.w : q0.w;
        unsigned uA = src[(size_t)cA * 32 + fl];
        unsigned uB = src[(size_t)cB * 32 + fl];
        unsigned uC = src[(size_t)cC * 32 + fl];
        unsigned uD = src[(size_t)cD * 32 + fl];
        a0 += bflo(uA); a1 += bfhi(uA);
        a0 += bflo(uB); a1 += bfhi(uB);
        a0 += bflo(uC); a1 += bfhi(uC);
        a0 += bflo(uD); a1 += bfhi(uD);
    }
    a0 += __shfl_xor(a0, 32, 64);
    a1 += __shfl_xor(a1, 32, 64);
    if (hi) return;
    float d2 = d2arr[r];
    size_t di = (size_t)r * 32 + fl;
    float sx, sy;
    if (FIRST) {
        sx = -d2 * a0;
        sy = -d2 * a1;
    } else {
        unsigned pu = prev[di];
        sx = fmaf(-2.f * d2, a0, -bflo(pu));
        sy = fmaf(-2.f * d2, a1, -bfhi(pu));
    }
    dst[di] = bfpack(sx, sy);
}

template <bool FINAL>
__global__ __launch_bounds__(256) void k_acc(const unsigned* __restrict__ s0,
                                             const unsigned* __restrict__ s1,
                                             const unsigned* __restrict__ s2,
                                             const unsigned* __restrict__ s3,
                                             const unsigned* __restrict__ s4,
                                             const unsigned* __restrict__ s5,
                                             const unsigned* __restrict__ s6,
                                             const float* __restrict__ cf,
                                             const float* __restrict__ bias,
                                             const float* __restrict__ rdinv,
                                             float* __restrict__ outacc, int n) {
    int i = blockIdx.x * 256 + threadIdx.x;
    if (i >= n * 32) return;
    float c0 = cf[0], c1 = cf[1], c2 = cf[2], c3 = cf[3], c4 = cf[4], c5 = cf[5], c6 = cf[6];
    unsigned u;
    float ax, ay;
    u = s0[i]; ax = c0 * bflo(u); ay = c0 * bfhi(u);
    u = s1[i]; ax = fmaf(c1, bflo(u), ax); ay = fmaf(c1, bfhi(u), ay);
    u = s2[i]; ax = fmaf(c2, bflo(u), ax); ay = fmaf(c2, bfhi(u), ay);
    u = s3[i]; ax = fmaf(c3, bflo(u), ax); ay = fmaf(c3, bfhi(u), ay);
    u = s4[i]; ax = fmaf(c4, bflo(u), ax); ay = fmaf(c4, bfhi(u), ay);
    u = s5[i]; ax = fmaf(c5, bflo(u), ax); ay = fmaf(c5, bfhi(u), ay);
    u = s6[i]; ax = fmaf(c6, bflo(u), ax); ay = fmaf(c6, bfhi(u), ay);
    float rd = rdinv[i >> 5];
    ax *= rd;
    ay *= rd;
    float2* op = (float2*)outacc + i;
    if (FINAL) {
        int f0 = (i & 31) * 2;
        float2 pv = *op;
        float vx = pv.x + ax + bias[f0];
        float vy = pv.y + ay + bias[f0 + 1];
        *op = make_float2(vx > 0.f ? vx : 0.f, vy > 0.f ? vy : 0.f);
    } else {
        *op = make_float2(ax, ay);
    }
}

// run-length compressed segment sum over sorted batch; wave = 32 nodes, lane = feature
__global__ void k_pool(const float* __restrict__ h, const int* __restrict__ batch,
                       float* __restrict__ sums, float* __restrict__ cntf, int n) {
    int wid = (blockIdx.x * blockDim.x + threadIdx.x) >> 6;
    int lane = threadIdx.x & 63;
    int start = wid * 32;
    if (start >= n) return;
    int end = start + 32;
    if (end > n) end = n;
    float acc = 0.f;
    int run = 0;
    int g = batch[start];
    for (int i = start; i < end; ++i) {
        int gi = batch[i];
        if (gi != g) {
            atomicAdd(&sums[g * 64 + lane], acc);
            if (lane == 0) atomicAdd(&cntf[g], (float)run);
            acc = 0.f;
            run = 0;
            g = gi;
        }
        acc += h[(size_t)i * 64 + lane];
        run++;
    }
    atomicAdd(&sums[g * 64 + lane], acc);
    if (lane == 0) atomicAdd(&cntf[g], (float)run);
}

// per-graph head
__global__ void k_head(const float* __restrict__ sums, const float* __restrict__ cntf,
                       const float* __restrict__ w1, const float* __restrict__ b1,
                       const float* __restrict__ w2, const float* __restrict__ b2,
                       float* __restrict__ out) {
    __shared__ float pl[64], gl[64], lg[NCLASSES];
    int g = blockIdx.x, t = threadIdx.x;
    float c = cntf[g];
    if (c < 1.f) c = 1.f;
    pl[t] = sums[g * 64 + t] / c;
    __syncthreads();
    float a = b1[t];
    for (int f = 0; f < 64; ++f) a += pl[f] * w1[f * 64 + t];
    gl[t] = a > 0.f ? a : 0.f;
    __syncthreads();
    if (t < NCLASSES) {
        float a2 = b2[t];
        for (int f = 0; f < 64; ++f) a2 += gl[f] * w2[f * NCLASSES + t];
        lg[t] = a2;
    }
    __syncthreads();
    if (t < NCLASSES) {
        float m = lg[0];
        for (int i = 1; i < NCLASSES; ++i) m = fmaxf(m, lg[i]);
        float s = 0.f;
        for (int i = 0; i < NCLASSES; ++i) s += expf(lg[i] - m);
        out[g * NCLASSES + t] = lg[t] - m - logf(s);
    }
}

// ---------------- host ----------------

extern "C" void kernel_launch(void* const* d_in, const int* in_sizes, int n_in,
                              void* d_out, int out_size, void* d_ws, size_t ws_size,
                              hipStream_t stream) {
    const float* x   = (const float*)d_in[0];
    const int*   ei  = (const int*)d_in[1];
    const int*   bat = (const int*)d_in[2];
    const float* W1  = (const float*)d_in[3];
    const float* th1 = (const float*)d_in[4];
    const float* b1  = (const float*)d_in[5];
    const float* Ws  = (const float*)d_in[6];
    const float* ths = (const float*)d_in[7];
    const float* bs  = (const float*)d_in[8];
    const float* l1w = (const float*)d_in[9];
    const float* l1b = (const float*)d_in[10];
    const float* l2w = (const float*)d_in[11];
    const float* l2b = (const float*)d_in[12];
    float* out = (float*)d_out;

    const int n  = in_sizes[2];
    const int ne = in_sizes[1] / 2;
    const int* erow = ei;
    const int* ecol = ei + ne;

    // workspace carve
    char* w = (char*)d_ws;
    size_t off = 0;
    auto carve = [&](size_t bytes) {
        void* p = w + off;
        off += align256(bytes);
        return p;
    };
    const size_t ne_pad = (size_t)ne + 7 * (size_t)n + 8;
    const size_t slabd = (size_t)(n + 1) * 32;
    int*   deg    = (int*)carve((size_t)n * 4);
    int*   rowptr = (int*)carve((size_t)(n + 1) * 4);
    int*   cursor = (int*)carve((size_t)n * 4);
    int*   bsum   = (int*)carve(1024 * 4);
    int*   ccol   = (int*)carve(ne_pad * 4);
    float* dinv   = (float*)carve((size_t)n * 4);
    float* d2     = (float*)carve((size_t)n * 4);
    float* rdinv  = (float*)carve((size_t)n * 4);
    float* coeff  = (float*)carve(3 * KORD * 4);
    float* sums   = (float*)carve((size_t)NGRAPHS * 64 * 4);
    float* cntf   = (float*)carve((size_t)NGRAPHS * 4);
    float* outacc = (float*)carve((size_t)n * 64 * 4);  // H
    unsigned* slabs = (unsigned*)carve(7 * slabd * 4);
    auto slab = [&](int s) { return slabs + (size_t)s * slabd; };
    (void)ws_size; (void)n_in; (void)out_size;

    const int nb256e = (ne + 255) / 256;
    const int nb256n = (n + 255) / 256;

    hipMemsetAsync(deg, 0, (size_t)n * 4, stream);
    hipMemsetAsync(sums, 0, (size_t)NGRAPHS * 64 * 4, stream);
    hipMemsetAsync(cntf, 0, (size_t)NGRAPHS * 4, stream);

    k_deg<<<nb256e, 256, 0, stream>>>(erow, deg, ne);
    k_dinv<<<nb256n, 256, 0, stream>>>(deg, dinv, d2, rdinv, n);
    k_scan1<<<nb256n, 256, 0, stream>>>(deg, rowptr, bsum, n);
    k_scan2<<<1, 1024, 0, stream>>>(bsum, nb256n);
    k_scan3<<<nb256n, 256, 0, stream>>>(rowptr, cursor, bsum, deg, n);
    k_filln<<<(int)((ne_pad + 255) / 256), 256, 0, stream>>>(ccol, (int)ne_pad, n);
    k_fill<<<nb256e, 256, 0, stream>>>(erow, ecol, cursor, ccol, ne);
    k_zrow<<<1, 256, 0, stream>>>(slabs, n);
    k_coeff<<<1, 64, 0, stream>>>(th1, ths, coeff);

    const int pb = (n + 3) / 4;
    const int n32 = n * 32;
    const int ab = (n32 + 255) / 256;
    int R = (n + GRIDC - 1) / GRIDC;
    size_t ldsBytes = (size_t)R * 64 * 4;

    for (int l = 0; l < 3; ++l) {
        const float* cf = coeff + l * KORD;
        const float* bias = (l == 0) ? b1 : bs + (l - 1) * HID;

        if (l == 0)
            k_gemm<FIN><<<(n + 63) / 64, 256, 0, stream>>>(x, W1, slab(0), dinv, n);
        else
            k_gemm<HID><<<(n + 63) / 64, 256, 0, stream>>>(outacc, Ws + (size_t)(l - 1) * HID * HID,
                                                           slab(0), dinv, n);

        // cooperative fused layer kernel (13 props + acc in LDS)
        unsigned* sA = slab(0);
        unsigned* sB = slab(1);
        void* args[] = {(void*)&rowptr, (void*)&ccol, (void*)&sA, (void*)&sB,
                        (void*)&d2, (void*)&rdinv, (void*)&cf, (void*)&bias,
                        (void*)&outacc, (void*)&n, (void*)&R};
        hipError_t err = hipLaunchCooperativeKernel((void*)k_layer, dim3(GRIDC), dim3(256),
                                                    args, (unsigned)ldsBytes, stream);
        if (err != hipSuccess) {
            // fallback: proven R8 sequence
            k_prop<true><<<pb, 256, 0, stream>>>(rowptr, ccol, slab(0), nullptr, slab(1), d2, n);
            for (int k = 2; k <= 6; ++k)
                k_prop<false><<<pb, 256, 0, stream>>>(rowptr, ccol, slab(k - 1), slab(k - 2), slab(k), d2, n);
            k_acc<false><<<ab, 256, 0, stream>>>(slab(0), slab(1), slab(2), slab(3), slab(4), slab(5),
                                                 slab(6), cf, nullptr, rdinv, outacc, n);
            for (int k = 7; k <= 13; ++k)
                k_prop<false><<<pb, 256, 0, stream>>>(rowptr, ccol, slab((k - 1) % 7), slab((k - 2) % 7),
                                                      slab(k % 7), d2, n);
            k_acc<true><<<ab, 256, 0, stream>>>(slab(0), slab(1), slab(2), slab(3), slab(4), slab(5),
                                                slab(6), cf + 7, bias, rdinv, outacc, n);
        }
    }

    const int poolwaves = (n + 31) / 32;
    const int poolblocks = (poolwaves * 64 + 255) / 256;
    k_pool<<<poolblocks, 256, 0, stream>>>(outacc, bat, sums, cntf, n);
    k_head<<<NGRAPHS, 64, 0, stream>>>(sums, cntf, l1w, l1b, l2w, l2b, out);
}

// Round 10
// 1834.009 us; speedup vs baseline: 7.4189x; 7.4189x over previous
//
#include <hip/hip_runtime.h>

#define NN 100000
#define NE 1600000
#define FIN 128
#define HID 64
#define HEADS 8
#define KORD 14
#define NGRAPHS 128
#define NCLASSES 10

static inline size_t align256(size_t x) { return (x + 255) & ~(size_t)255; }

// round-to-nearest-even f32 -> bf16 (as uint16 in low bits)
__device__ __forceinline__ unsigned bfr(float x) {
    unsigned u = __float_as_uint(x);
    return (u + 0x7fffu + ((u >> 16) & 1u)) >> 16;
}
__device__ __forceinline__ unsigned bfpack(float lo, float hi) {
    return bfr(lo) | (bfr(hi) << 16);
}
__device__ __forceinline__ float bflo(unsigned u) { return __uint_as_float(u << 16); }
__device__ __forceinline__ float bfhi(unsigned u) { return __uint_as_float(u & 0xffff0000u); }

// ---------------- setup kernels ----------------

__global__ void k_deg(const int* __restrict__ row, int* __restrict__ deg, int ne) {
    int e = blockIdx.x * 256 + threadIdx.x;
    if (e < ne) atomicAdd(&deg[row[e]], 1);
}

// dinv = rsqrt(max(deg,1)); d2 = 1/max(deg,1); rdinv = sqrt(max(deg,1))
__global__ void k_dinv(const int* __restrict__ deg, float* __restrict__ dinv,
                       float* __restrict__ d2, float* __restrict__ rdinv, int n) {
    int i = blockIdx.x * 256 + threadIdx.x;
    if (i < n) {
        float d = (float)deg[i];
        if (d < 1.f) d = 1.f;
        dinv[i] = rsqrtf(d);
        d2[i] = 1.f / d;
        rdinv[i] = sqrtf(d);
    }
}

// exclusive scan phase 1: per-block scan of PADDED degrees ((deg+7)&~7)
__global__ void k_scan1(const int* __restrict__ deg, int* __restrict__ rowptr,
                        int* __restrict__ bsum, int n) {
    __shared__ int s[256];
    int t = threadIdx.x;
    int i = blockIdx.x * 256 + t;
    int v = (i < n) ? ((deg[i] + 7) & ~7) : 0;
    s[t] = v;
    __syncthreads();
    for (int off = 1; off < 256; off <<= 1) {
        int add = (t >= off) ? s[t - off] : 0;
        __syncthreads();
        s[t] += add;
        __syncthreads();
    }
    if (i < n) rowptr[i] = s[t] - v;  // exclusive within block
    if (t == 255) bsum[blockIdx.x] = s[255];
}

// phase 2: single-block exclusive scan of block sums (nb <= 1024)
__global__ void k_scan2(int* __restrict__ bsum, int nb) {
    __shared__ int s[1024];
    int t = threadIdx.x;
    int v = (t < nb) ? bsum[t] : 0;
    s[t] = v;
    __syncthreads();
    for (int off = 1; off < 1024; off <<= 1) {
        int add = (t >= off) ? s[t - off] : 0;
        __syncthreads();
        s[t] += add;
        __syncthreads();
    }
    if (t < nb) bsum[t] = s[t] - v;  // exclusive
}

// phase 3: add block offsets; init cursor; write rowptr[n] (total padded edges)
__global__ void k_scan3(int* __restrict__ rowptr, int* __restrict__ cursor,
                        const int* __restrict__ bsum, const int* __restrict__ deg, int n) {
    int i = blockIdx.x * 256 + threadIdx.x;
    if (i < n) {
        int v = rowptr[i] + bsum[i >> 8];
        rowptr[i] = v;
        cursor[i] = v;
        if (i == n - 1) rowptr[n] = v + ((deg[i] + 7) & ~7);
    }
}

// pre-fill ccol with the zero-row index n (pad slots read row n == 0)
__global__ void k_filln(int* __restrict__ ccol, int npad, int n) {
    int i = blockIdx.x * 256 + threadIdx.x;
    if (i < npad) ccol[i] = n;
}

// fill CSR cols (weights are implicit in S-space)
__global__ void k_fill(const int* __restrict__ row, const int* __restrict__ col,
                       int* __restrict__ cursor, int* __restrict__ ccol, int ne) {
    int e = blockIdx.x * 256 + threadIdx.x;
    if (e >= ne) return;
    int pos = atomicAdd(&cursor[row[e]], 1);
    ccol[pos] = col[e];
}

// zero the pad row (row n) of all 7 slabs (each slab = (n+1) x 32 dwords)
__global__ void k_zrow(unsigned* __restrict__ slabs, int n) {
    int t = threadIdx.x;
    if (t >= 7 * 32) return;
    int sp = t >> 5;  // slab 0..6
    int q = t & 31;
    slabs[(size_t)sp * (size_t)(n + 1) * 32 + (size_t)n * 32 + q] = 0;
}

// coeff[l][k] = mean over heads of theta[l][h][k]
__global__ void k_coeff(const float* __restrict__ th1, const float* __restrict__ ths,
                        float* __restrict__ coeff) {
    int i = threadIdx.x;
    if (i >= 3 * KORD) return;
    int l = i / KORD, k = i % KORD;
    const float* t = (l == 0) ? th1 : ths + (l - 1) * HEADS * KORD;
    float s = 0.f;
    for (int h = 0; h < HEADS; ++h) s += t[h * KORD + k];
    coeff[i] = s * (1.f / HEADS);
}

// ---------------- main compute kernels ----------------

// S0 = dinv * (h @ W), written as bf16 [n][64] (= [n][32] dwords) slab.
// block = 256 threads, tile = 64 rows x 64 cols, thread computes 4 rows x 4 cols.
template <int F>
__global__ __launch_bounds__(256) void k_gemm(const float* __restrict__ h,
                                              const float* __restrict__ W,
                                              unsigned* __restrict__ slab0,
                                              const float* __restrict__ dinv, int n) {
    __shared__ __align__(16) float Wl[F * 64];
    __shared__ float hl[64][F + 1];
    int tid = threadIdx.x;
    int row0 = blockIdx.x * 64;
    int nrows = n - row0;
    if (nrows > 64) nrows = 64;

    for (int i = tid; i < F * 64; i += 256) Wl[i] = W[i];
    for (int i = tid; i < nrows * F; i += 256) hl[i / F][i % F] = h[(size_t)row0 * F + i];
    __syncthreads();

    int rq = tid >> 4;
    int c0 = (tid & 15) * 4;
    float4 acc0 = {0, 0, 0, 0}, acc1 = {0, 0, 0, 0}, acc2 = {0, 0, 0, 0}, acc3 = {0, 0, 0, 0};
#pragma unroll 4
    for (int f = 0; f < F; ++f) {
        const float4 wv = *(const float4*)&Wl[f * 64 + c0];
        float h0 = hl[rq * 4 + 0][f];
        float h1 = hl[rq * 4 + 1][f];
        float h2 = hl[rq * 4 + 2][f];
        float h3 = hl[rq * 4 + 3][f];
        acc0.x = fmaf(h0, wv.x, acc0.x); acc0.y = fmaf(h0, wv.y, acc0.y);
        acc0.z = fmaf(h0, wv.z, acc0.z); acc0.w = fmaf(h0, wv.w, acc0.w);
        acc1.x = fmaf(h1, wv.x, acc1.x); acc1.y = fmaf(h1, wv.y, acc1.y);
        acc1.z = fmaf(h1, wv.z, acc1.z); acc1.w = fmaf(h1, wv.w, acc1.w);
        acc2.x = fmaf(h2, wv.x, acc2.x); acc2.y = fmaf(h2, wv.y, acc2.y);
        acc2.z = fmaf(h2, wv.z, acc2.z); acc2.w = fmaf(h2, wv.w, acc2.w);
        acc3.x = fmaf(h3, wv.x, acc3.x); acc3.y = fmaf(h3, wv.y, acc3.y);
        acc3.z = fmaf(h3, wv.z, acc3.z); acc3.w = fmaf(h3, wv.w, acc3.w);
    }
    int rem = nrows - rq * 4;
    float4 accs[4] = {acc0, acc1, acc2, acc3};
    int qd = c0 >> 1;
#pragma unroll
    for (int r = 0; r < 4; ++r) {
        if (r < rem) {
            int row = row0 + rq * 4 + r;
            float dv = dinv[row];
            uint2 p;
            p.x = bfpack(accs[r].x * dv, accs[r].y * dv);
            p.y = bfpack(accs[r].z * dv, accs[r].w * dv);
            *(uint2*)(slab0 + (size_t)row * 32 + qd) = p;
        }
    }
}

// S-space Chebyshev prop. Wave = one row; low half lanes: edges 0-3 of the 8-block,
// high half: edges 4-7. Each lane loads 1 dword (2 bf16 feats) per edge -> 128 B/edge
// coalesced, 4 independent gathers in flight. Rows padded to x8 with col=n (zero row).
// MODE 0: k=1  : S1 = -d2 * sum
// MODE 1: mid  : S_k = -2*d2*sum - S_{k-2}
// MODE 2: k=6  : as MODE 1, plus outacc = rdinv * sum_{j=0..6} cfb[j]*S_j
//                (x0..x3 = S0..S3, prev = S4, x5 = S5, fresh = S6)
// MODE 3: k=13 : as MODE 1, plus outacc = relu(outacc + rdinv * sum cfb[j]*S_{7+j} + bias)
//                (x0..x3 = S7..S10, prev = S11, x5 = S12, fresh = S13)
template <int MODE>
__global__ __launch_bounds__(256) void k_prop(const int* __restrict__ rowptr,
                                              const int* __restrict__ ccol,
                                              const unsigned* __restrict__ src,
                                              const unsigned* __restrict__ prev,
                                              unsigned* __restrict__ dst,
                                              const float* __restrict__ d2arr,
                                              const unsigned* __restrict__ x0,
                                              const unsigned* __restrict__ x1,
                                              const unsigned* __restrict__ x2,
                                              const unsigned* __restrict__ x3,
                                              const unsigned* __restrict__ x5,
                                              const float* __restrict__ cfb,
                                              const float* __restrict__ rdinv,
                                              const float* __restrict__ bias,
                                              float* __restrict__ outacc, int n) {
    int r = (blockIdx.x * 256 + threadIdx.x) >> 6;
    int lane = threadIdx.x & 63;
    if (r >= n) return;
    r = __builtin_amdgcn_readfirstlane(r);
    const int e0 = __builtin_amdgcn_readfirstlane(rowptr[r]);
    const int e1 = __builtin_amdgcn_readfirstlane(rowptr[r + 1]);
    const bool hi = lane >= 32;
    const int fl = lane & 31;
    float a0 = 0.f, a1 = 0.f;
    for (int e = e0; e < e1; e += 8) {
        const int4* q = (const int4*)(ccol + e);
        int4 q0 = q[0];
        int4 q1 = q[1];
        int cA = hi ? q1.x : q0.x;
        int cB = hi ? q1.y : q0.y;
        int cC = hi ? q1.z : q0.z;
        int cD = hi ? q1.w : q0.w;
        unsigned uA = src[(size_t)cA * 32 + fl];
        unsigned uB = src[(size_t)cB * 32 + fl];
        unsigned uC = src[(size_t)cC * 32 + fl];
        unsigned uD = src[(size_t)cD * 32 + fl];
        a0 += bflo(uA); a1 += bfhi(uA);
        a0 += bflo(uB); a1 += bfhi(uB);
        a0 += bflo(uC); a1 += bfhi(uC);
        a0 += bflo(uD); a1 += bfhi(uD);
    }
    a0 += __shfl_xor(a0, 32, 64);
    a1 += __shfl_xor(a1, 32, 64);
    if (hi) return;
    float d2 = d2arr[r];
    size_t di = (size_t)r * 32 + fl;
    float sx, sy;
    unsigned pu = 0;
    if (MODE == 0) {
        sx = -d2 * a0;
        sy = -d2 * a1;
    } else {
        pu = prev[di];
        sx = fmaf(-2.f * d2, a0, -bflo(pu));
        sy = fmaf(-2.f * d2, a1, -bfhi(pu));
    }
    dst[di] = bfpack(sx, sy);
    if (MODE >= 2) {
        float cA0 = cfb[0], cA1 = cfb[1], cA2 = cfb[2], cA3 = cfb[3];
        float cA4 = cfb[4], cA5 = cfb[5], cA6 = cfb[6];
        unsigned u0 = x0[di], u1 = x1[di], u2 = x2[di], u3 = x3[di], u5 = x5[di];
        float ax = cA0 * bflo(u0);
        float ay = cA0 * bfhi(u0);
        ax = fmaf(cA1, bflo(u1), ax); ay = fmaf(cA1, bfhi(u1), ay);
        ax = fmaf(cA2, bflo(u2), ax); ay = fmaf(cA2, bfhi(u2), ay);
        ax = fmaf(cA3, bflo(u3), ax); ay = fmaf(cA3, bfhi(u3), ay);
        ax = fmaf(cA4, bflo(pu), ax); ay = fmaf(cA4, bfhi(pu), ay);
        ax = fmaf(cA5, bflo(u5), ax); ay = fmaf(cA5, bfhi(u5), ay);
        ax = fmaf(cA6, sx, ax);       ay = fmaf(cA6, sy, ay);
        float rd = rdinv[r];
        ax *= rd;
        ay *= rd;
        float2* op = (float2*)outacc + di;
        if (MODE == 2) {
            *op = make_float2(ax, ay);
        } else {
            float2 pv = *op;
            int f0 = fl * 2;
            float vx = pv.x + ax + bias[f0];
            float vy = pv.y + ay + bias[f0 + 1];
            *op = make_float2(vx > 0.f ? vx : 0.f, vy > 0.f ? vy : 0.f);
        }
    }
}

// run-length compressed segment sum over sorted batch; wave = 32 nodes, lane = feature
__global__ void k_pool(const float* __restrict__ h, const int* __restrict__ batch,
                       float* __restrict__ sums, float* __restrict__ cntf, int n) {
    int wid = (blockIdx.x * blockDim.x + threadIdx.x) >> 6;
    int lane = threadIdx.x & 63;
    int start = wid * 32;
    if (start >= n) return;
    int end = start + 32;
    if (end > n) end = n;
    float acc = 0.f;
    int run = 0;
    int g = batch[start];
    for (int i = start; i < end; ++i) {
        int gi = batch[i];
        if (gi != g) {
            atomicAdd(&sums[g * 64 + lane], acc);
            if (lane == 0) atomicAdd(&cntf[g], (float)run);
            acc = 0.f;
            run = 0;
            g = gi;
        }
        acc += h[(size_t)i * 64 + lane];
        run++;
    }
    atomicAdd(&sums[g * 64 + lane], acc);
    if (lane == 0) atomicAdd(&cntf[g], (float)run);
}

// per-graph head: pooled = sums/cnt ; g = relu(pooled@w1+b1) ; logits = g@w2+b2 ; log_softmax
__global__ void k_head(const float* __restrict__ sums, const float* __restrict__ cntf,
                       const float* __restrict__ w1, const float* __restrict__ b1,
                       const float* __restrict__ w2, const float* __restrict__ b2,
                       float* __restrict__ out) {
    __shared__ float pl[64], gl[64], lg[NCLASSES];
    int g = blockIdx.x, t = threadIdx.x;
    float c = cntf[g];
    if (c < 1.f) c = 1.f;
    pl[t] = sums[g * 64 + t] / c;
    __syncthreads();
    float a = b1[t];
    for (int f = 0; f < 64; ++f) a += pl[f] * w1[f * 64 + t];
    gl[t] = a > 0.f ? a : 0.f;
    __syncthreads();
    if (t < NCLASSES) {
        float a2 = b2[t];
        for (int f = 0; f < 64; ++f) a2 += gl[f] * w2[f * NCLASSES + t];
        lg[t] = a2;
    }
    __syncthreads();
    if (t < NCLASSES) {
        float m = lg[0];
        for (int i = 1; i < NCLASSES; ++i) m = fmaxf(m, lg[i]);
        float s = 0.f;
        for (int i = 0; i < NCLASSES; ++i) s += expf(lg[i] - m);
        out[g * NCLASSES + t] = lg[t] - m - logf(s);
    }
}

// ---------------- host ----------------

extern "C" void kernel_launch(void* const* d_in, const int* in_sizes, int n_in,
                              void* d_out, int out_size, void* d_ws, size_t ws_size,
                              hipStream_t stream) {
    const float* x   = (const float*)d_in[0];
    const int*   ei  = (const int*)d_in[1];
    const int*   bat = (const int*)d_in[2];
    const float* W1  = (const float*)d_in[3];
    const float* th1 = (const float*)d_in[4];
    const float* b1  = (const float*)d_in[5];
    const float* Ws  = (const float*)d_in[6];
    const float* ths = (const float*)d_in[7];
    const float* bs  = (const float*)d_in[8];
    const float* l1w = (const float*)d_in[9];
    const float* l1b = (const float*)d_in[10];
    const float* l2w = (const float*)d_in[11];
    const float* l2b = (const float*)d_in[12];
    float* out = (float*)d_out;

    const int n  = in_sizes[2];
    const int ne = in_sizes[1] / 2;
    const int* erow = ei;
    const int* ecol = ei + ne;

    // workspace carve
    char* w = (char*)d_ws;
    size_t off = 0;
    auto carve = [&](size_t bytes) {
        void* p = w + off;
        off += align256(bytes);
        return p;
    };
    const size_t ne_pad = (size_t)ne + 7 * (size_t)n + 8;
    const size_t slabd = (size_t)(n + 1) * 32;
    int*   deg    = (int*)carve((size_t)n * 4);
    int*   rowptr = (int*)carve((size_t)(n + 1) * 4);
    int*   cursor = (int*)carve((size_t)n * 4);
    int*   bsum   = (int*)carve(1024 * 4);
    int*   ccol   = (int*)carve(ne_pad * 4);
    float* dinv   = (float*)carve((size_t)n * 4);
    float* d2     = (float*)carve((size_t)n * 4);
    float* rdinv  = (float*)carve((size_t)n * 4);
    float* coeff  = (float*)carve(3 * KORD * 4);
    float* sums   = (float*)carve((size_t)NGRAPHS * 64 * 4);
    float* cntf   = (float*)carve((size_t)NGRAPHS * 4);
    float* outacc = (float*)carve((size_t)n * 64 * 4);  // doubles as H
    unsigned* slabs = (unsigned*)carve(7 * slabd * 4);
    auto slab = [&](int s) { return slabs + (size_t)s * slabd; };
    (void)ws_size; (void)n_in; (void)out_size;

    const int nb256e = (ne + 255) / 256;
    const int nb256n = (n + 255) / 256;

    hipMemsetAsync(deg, 0, (size_t)n * 4, stream);
    hipMemsetAsync(sums, 0, (size_t)NGRAPHS * 64 * 4, stream);
    hipMemsetAsync(cntf, 0, (size_t)NGRAPHS * 4, stream);

    k_deg<<<nb256e, 256, 0, stream>>>(erow, deg, ne);
    k_dinv<<<nb256n, 256, 0, stream>>>(deg, dinv, d2, rdinv, n);
    k_scan1<<<nb256n, 256, 0, stream>>>(deg, rowptr, bsum, n);
    k_scan2<<<1, 1024, 0, stream>>>(bsum, nb256n);
    k_scan3<<<nb256n, 256, 0, stream>>>(rowptr, cursor, bsum, deg, n);
    k_filln<<<(int)((ne_pad + 255) / 256), 256, 0, stream>>>(ccol, (int)ne_pad, n);
    k_fill<<<nb256e, 256, 0, stream>>>(erow, ecol, cursor, ccol, ne);
    k_zrow<<<1, 256, 0, stream>>>(slabs, n);
    k_coeff<<<1, 64, 0, stream>>>(th1, ths, coeff);

    const int pb = (n + 3) / 4;  // 4 waves (rows) per 256-thread block

    for (int l = 0; l < 3; ++l) {
        const float* cf = coeff + l * KORD;
        const float* bias = (l == 0) ? b1 : bs + (l - 1) * HID;

        if (l == 0)
            k_gemm<FIN><<<(n + 63) / 64, 256, 0, stream>>>(x, W1, slab(0), dinv, n);
        else
            k_gemm<HID><<<(n + 63) / 64, 256, 0, stream>>>(outacc, Ws + (size_t)(l - 1) * HID * HID,
                                                           slab(0), dinv, n);

        // k=1: S1 = L~_S S0
        k_prop<0><<<pb, 256, 0, stream>>>(rowptr, ccol, slab(0), nullptr, slab(1), d2,
                                          nullptr, nullptr, nullptr, nullptr, nullptr,
                                          nullptr, nullptr, nullptr, nullptr, n);
        // k=2..5
        for (int k = 2; k <= 5; ++k)
            k_prop<1><<<pb, 256, 0, stream>>>(rowptr, ccol, slab(k - 1), slab(k - 2), slab(k), d2,
                                              nullptr, nullptr, nullptr, nullptr, nullptr,
                                              nullptr, nullptr, nullptr, nullptr, n);
        // k=6 + fused acc of S0..S6
        k_prop<2><<<pb, 256, 0, stream>>>(rowptr, ccol, slab(5), slab(4), slab(6), d2,
                                          slab(0), slab(1), slab(2), slab(3), slab(5),
                                          cf, rdinv, nullptr, outacc, n);
        // k=7..12 (slab k%7)
        for (int k = 7; k <= 12; ++k)
            k_prop<1><<<pb, 256, 0, stream>>>(rowptr, ccol, slab((k - 1) % 7), slab((k - 2) % 7),
                                              slab(k % 7), d2,
                                              nullptr, nullptr, nullptr, nullptr, nullptr,
                                              nullptr, nullptr, nullptr, nullptr, n);
        // k=13 + fused final acc of S7..S13, bias, relu -> H
        k_prop<3><<<pb, 256, 0, stream>>>(rowptr, ccol, slab(5), slab(4), slab(6), d2,
                                          slab(0), slab(1), slab(2), slab(3), slab(5),
                                          cf + 7, rdinv, bias, outacc, n);
    }

    const int poolwaves = (n + 31) / 32;
    const int poolblocks = (poolwaves * 64 + 255) / 256;
    k_pool<<<poolblocks, 256, 0, stream>>>(outacc, bat, sums, cntf, n);
    k_head<<<NGRAPHS, 64, 0, stream>>>(sums, cntf, l1w, l1b, l2w, l2b, out);
}

// Round 11
// 1787.254 us; speedup vs baseline: 7.6130x; 1.0262x over previous
//
#include <hip/hip_runtime.h>

#define NN 100000
#define NE 1600000
#define FIN 128
#define HID 64
#define HEADS 8
#define KORD 14
#define NGRAPHS 128
#define NCLASSES 10

static inline size_t align256(size_t x) { return (x + 255) & ~(size_t)255; }

// round-to-nearest-even f32 -> bf16 (as uint16 in low bits)
__device__ __forceinline__ unsigned bfr(float x) {
    unsigned u = __float_as_uint(x);
    return (u + 0x7fffu + ((u >> 16) & 1u)) >> 16;
}
__device__ __forceinline__ unsigned bfpack(float lo, float hi) {
    return bfr(lo) | (bfr(hi) << 16);
}
__device__ __forceinline__ float bflo(unsigned u) { return __uint_as_float(u << 16); }
__device__ __forceinline__ float bfhi(unsigned u) { return __uint_as_float(u & 0xffff0000u); }

// ---------------- setup kernels ----------------

__global__ void k_deg(const int* __restrict__ row, int* __restrict__ deg, int ne) {
    int e = blockIdx.x * 256 + threadIdx.x;
    if (e < ne) atomicAdd(&deg[row[e]], 1);
}

// dinv = rsqrt(max(deg,1)); d2 = 1/max(deg,1); rdinv = sqrt(max(deg,1))
__global__ void k_dinv(const int* __restrict__ deg, float* __restrict__ dinv,
                       float* __restrict__ d2, float* __restrict__ rdinv, int n) {
    int i = blockIdx.x * 256 + threadIdx.x;
    if (i < n) {
        float d = (float)deg[i];
        if (d < 1.f) d = 1.f;
        dinv[i] = rsqrtf(d);
        d2[i] = 1.f / d;
        rdinv[i] = sqrtf(d);
    }
}

// exclusive scan phase 1: per-block scan of PADDED degrees ((deg+7)&~7)
__global__ void k_scan1(const int* __restrict__ deg, int* __restrict__ rowptr,
                        int* __restrict__ bsum, int n) {
    __shared__ int s[256];
    int t = threadIdx.x;
    int i = blockIdx.x * 256 + t;
    int v = (i < n) ? ((deg[i] + 7) & ~7) : 0;
    s[t] = v;
    __syncthreads();
    for (int off = 1; off < 256; off <<= 1) {
        int add = (t >= off) ? s[t - off] : 0;
        __syncthreads();
        s[t] += add;
        __syncthreads();
    }
    if (i < n) rowptr[i] = s[t] - v;  // exclusive within block
    if (t == 255) bsum[blockIdx.x] = s[255];
}

// phase 2: single-block exclusive scan of block sums (nb <= 1024)
__global__ void k_scan2(int* __restrict__ bsum, int nb) {
    __shared__ int s[1024];
    int t = threadIdx.x;
    int v = (t < nb) ? bsum[t] : 0;
    s[t] = v;
    __syncthreads();
    for (int off = 1; off < 1024; off <<= 1) {
        int add = (t >= off) ? s[t - off] : 0;
        __syncthreads();
        s[t] += add;
        __syncthreads();
    }
    if (t < nb) bsum[t] = s[t] - v;  // exclusive
}

// phase 3: add block offsets; init cursor; write rowptr[n] (total padded edges)
__global__ void k_scan3(int* __restrict__ rowptr, int* __restrict__ cursor,
                        const int* __restrict__ bsum, const int* __restrict__ deg, int n) {
    int i = blockIdx.x * 256 + threadIdx.x;
    if (i < n) {
        int v = rowptr[i] + bsum[i >> 8];
        rowptr[i] = v;
        cursor[i] = v;
        if (i == n - 1) rowptr[n] = v + ((deg[i] + 7) & ~7);
    }
}

// pre-fill ccol with the zero-row index n (pad slots read row n == 0)
__global__ void k_filln(int* __restrict__ ccol, int npad, int n) {
    int i = blockIdx.x * 256 + threadIdx.x;
    if (i < npad) ccol[i] = n;
}

// fill CSR cols (weights are implicit in S-space)
__global__ void k_fill(const int* __restrict__ row, const int* __restrict__ col,
                       int* __restrict__ cursor, int* __restrict__ ccol, int ne) {
    int e = blockIdx.x * 256 + threadIdx.x;
    if (e >= ne) return;
    int pos = atomicAdd(&cursor[row[e]], 1);
    ccol[pos] = col[e];
}

// zero the pad row (row n) of all 7 slabs (each slab = (n+1) x 32 dwords)
__global__ void k_zrow(unsigned* __restrict__ slabs, int n) {
    int t = threadIdx.x;
    if (t >= 7 * 32) return;
    int sp = t >> 5;  // slab 0..6
    int q = t & 31;
    slabs[(size_t)sp * (size_t)(n + 1) * 32 + (size_t)n * 32 + q] = 0;
}

// coeff[l][k] = mean over heads of theta[l][h][k]
__global__ void k_coeff(const float* __restrict__ th1, const float* __restrict__ ths,
                        float* __restrict__ coeff) {
    int i = threadIdx.x;
    if (i >= 3 * KORD) return;
    int l = i / KORD, k = i % KORD;
    const float* t = (l == 0) ? th1 : ths + (l - 1) * HEADS * KORD;
    float s = 0.f;
    for (int h = 0; h < HEADS; ++h) s += t[h * KORD + k];
    coeff[i] = s * (1.f / HEADS);
}

// ---------------- main compute kernels ----------------

// S0 = dinv * (h @ W), written as bf16 [n][64] (= [n][32] dwords) slab.
// block = 256 threads, tile = 64 rows x 64 cols, thread computes 4 rows x 4 cols.
template <int F>
__global__ __launch_bounds__(256) void k_gemm(const float* __restrict__ h,
                                              const float* __restrict__ W,
                                              unsigned* __restrict__ slab0,
                                              const float* __restrict__ dinv, int n) {
    __shared__ __align__(16) float Wl[F * 64];
    __shared__ float hl[64][F + 1];
    int tid = threadIdx.x;
    int row0 = blockIdx.x * 64;
    int nrows = n - row0;
    if (nrows > 64) nrows = 64;

    for (int i = tid; i < F * 64; i += 256) Wl[i] = W[i];
    for (int i = tid; i < nrows * F; i += 256) hl[i / F][i % F] = h[(size_t)row0 * F + i];
    __syncthreads();

    int rq = tid >> 4;
    int c0 = (tid & 15) * 4;
    float4 acc0 = {0, 0, 0, 0}, acc1 = {0, 0, 0, 0}, acc2 = {0, 0, 0, 0}, acc3 = {0, 0, 0, 0};
#pragma unroll 4
    for (int f = 0; f < F; ++f) {
        const float4 wv = *(const float4*)&Wl[f * 64 + c0];
        float h0 = hl[rq * 4 + 0][f];
        float h1 = hl[rq * 4 + 1][f];
        float h2 = hl[rq * 4 + 2][f];
        float h3 = hl[rq * 4 + 3][f];
        acc0.x = fmaf(h0, wv.x, acc0.x); acc0.y = fmaf(h0, wv.y, acc0.y);
        acc0.z = fmaf(h0, wv.z, acc0.z); acc0.w = fmaf(h0, wv.w, acc0.w);
        acc1.x = fmaf(h1, wv.x, acc1.x); acc1.y = fmaf(h1, wv.y, acc1.y);
        acc1.z = fmaf(h1, wv.z, acc1.z); acc1.w = fmaf(h1, wv.w, acc1.w);
        acc2.x = fmaf(h2, wv.x, acc2.x); acc2.y = fmaf(h2, wv.y, acc2.y);
        acc2.z = fmaf(h2, wv.z, acc2.z); acc2.w = fmaf(h2, wv.w, acc2.w);
        acc3.x = fmaf(h3, wv.x, acc3.x); acc3.y = fmaf(h3, wv.y, acc3.y);
        acc3.z = fmaf(h3, wv.z, acc3.z); acc3.w = fmaf(h3, wv.w, acc3.w);
    }
    int rem = nrows - rq * 4;
    float4 accs[4] = {acc0, acc1, acc2, acc3};
    int qd = c0 >> 1;
#pragma unroll
    for (int r = 0; r < 4; ++r) {
        if (r < rem) {
            int row = row0 + rq * 4 + r;
            float dv = dinv[row];
            uint2 p;
            p.x = bfpack(accs[r].x * dv, accs[r].y * dv);
            p.y = bfpack(accs[r].z * dv, accs[r].w * dv);
            *(uint2*)(slab0 + (size_t)row * 32 + qd) = p;
        }
    }
}

// S-space Chebyshev prop, dwordx2 gather: 16 lanes per edge, each lane loads uint2
// (4 bf16 feats, 8 B) -> one 64-lane VMEM instr covers 4 edges. Main loop: 16 edges
// with 4 independent gathers in flight; 8-edge tail. Rows padded to x8 with col=n.
// MODE 0: k=1  : S1 = -d2 * sum
// MODE 1: mid  : S_k = -2*d2*sum - S_{k-2}
// MODE 2: k=6  : as MODE 1, plus outacc = rdinv * sum_{j=0..6} cfb[j]*S_j
// MODE 3: k=13 : as MODE 1, plus outacc = relu(outacc + rdinv * sum cfb[j]*S_{7+j} + bias)
template <int MODE>
__global__ __launch_bounds__(256) void k_prop(const int* __restrict__ rowptr,
                                              const int* __restrict__ ccol,
                                              const unsigned* __restrict__ src,
                                              const unsigned* __restrict__ prev,
                                              unsigned* __restrict__ dst,
                                              const float* __restrict__ d2arr,
                                              const unsigned* __restrict__ x0,
                                              const unsigned* __restrict__ x1,
                                              const unsigned* __restrict__ x2,
                                              const unsigned* __restrict__ x3,
                                              const unsigned* __restrict__ x5,
                                              const float* __restrict__ cfb,
                                              const float* __restrict__ rdinv,
                                              const float* __restrict__ bias,
                                              float* __restrict__ outacc, int n) {
    int r = (blockIdx.x * 256 + threadIdx.x) >> 6;
    int lane = threadIdx.x & 63;
    if (r >= n) return;
    r = __builtin_amdgcn_readfirstlane(r);
    const int e0 = __builtin_amdgcn_readfirstlane(rowptr[r]);
    const int e1 = __builtin_amdgcn_readfirstlane(rowptr[r + 1]);
    const int g = lane >> 4;    // edge slot 0..3
    const int fl = lane & 15;   // uint2 index within the 128-B row
    const uint2* s2 = (const uint2*)src;
    float a0 = 0.f, a1 = 0.f, a2 = 0.f, a3 = 0.f;
    int e = e0;
    for (; e + 16 <= e1; e += 16) {
        int ca = ccol[e + g];
        int cb = ccol[e + 4 + g];
        int cc = ccol[e + 8 + g];
        int cd = ccol[e + 12 + g];
        uint2 uA = s2[(size_t)ca * 16 + fl];
        uint2 uB = s2[(size_t)cb * 16 + fl];
        uint2 uC = s2[(size_t)cc * 16 + fl];
        uint2 uD = s2[(size_t)cd * 16 + fl];
        a0 += bflo(uA.x); a1 += bfhi(uA.x); a2 += bflo(uA.y); a3 += bfhi(uA.y);
        a0 += bflo(uB.x); a1 += bfhi(uB.x); a2 += bflo(uB.y); a3 += bfhi(uB.y);
        a0 += bflo(uC.x); a1 += bfhi(uC.x); a2 += bflo(uC.y); a3 += bfhi(uC.y);
        a0 += bflo(uD.x); a1 += bfhi(uD.x); a2 += bflo(uD.y); a3 += bfhi(uD.y);
    }
    if (e < e1) {  // 8-edge tail
        int ca = ccol[e + g];
        int cb = ccol[e + 4 + g];
        uint2 uA = s2[(size_t)ca * 16 + fl];
        uint2 uB = s2[(size_t)cb * 16 + fl];
        a0 += bflo(uA.x); a1 += bfhi(uA.x); a2 += bflo(uA.y); a3 += bfhi(uA.y);
        a0 += bflo(uB.x); a1 += bfhi(uB.x); a2 += bflo(uB.y); a3 += bfhi(uB.y);
    }
    // reduce the 4 edge groups
    a0 += __shfl_xor(a0, 16, 64); a1 += __shfl_xor(a1, 16, 64);
    a2 += __shfl_xor(a2, 16, 64); a3 += __shfl_xor(a3, 16, 64);
    a0 += __shfl_xor(a0, 32, 64); a1 += __shfl_xor(a1, 32, 64);
    a2 += __shfl_xor(a2, 32, 64); a3 += __shfl_xor(a3, 32, 64);
    if (lane >= 16) return;
    float d2 = d2arr[r];
    size_t di2 = (size_t)r * 16 + fl;  // uint2 index
    float s0v, s1v, s2v, s3v;
    uint2 pu = make_uint2(0u, 0u);
    if (MODE == 0) {
        s0v = -d2 * a0;
        s1v = -d2 * a1;
        s2v = -d2 * a2;
        s3v = -d2 * a3;
    } else {
        pu = ((const uint2*)prev)[di2];
        float m2 = -2.f * d2;
        s0v = fmaf(m2, a0, -bflo(pu.x));
        s1v = fmaf(m2, a1, -bfhi(pu.x));
        s2v = fmaf(m2, a2, -bflo(pu.y));
        s3v = fmaf(m2, a3, -bfhi(pu.y));
    }
    ((uint2*)dst)[di2] = make_uint2(bfpack(s0v, s1v), bfpack(s2v, s3v));
    if (MODE >= 2) {
        float cA0 = cfb[0], cA1 = cfb[1], cA2 = cfb[2], cA3 = cfb[3];
        float cA4 = cfb[4], cA5 = cfb[5], cA6 = cfb[6];
        uint2 u0 = ((const uint2*)x0)[di2];
        uint2 u1 = ((const uint2*)x1)[di2];
        uint2 u2 = ((const uint2*)x2)[di2];
        uint2 u3 = ((const uint2*)x3)[di2];
        uint2 u5 = ((const uint2*)x5)[di2];
        float b0 = cA0 * bflo(u0.x), b1 = cA0 * bfhi(u0.x);
        float b2 = cA0 * bflo(u0.y), b3 = cA0 * bfhi(u0.y);
        b0 = fmaf(cA1, bflo(u1.x), b0); b1 = fmaf(cA1, bfhi(u1.x), b1);
        b2 = fmaf(cA1, bflo(u1.y), b2); b3 = fmaf(cA1, bfhi(u1.y), b3);
        b0 = fmaf(cA2, bflo(u2.x), b0); b1 = fmaf(cA2, bfhi(u2.x), b1);
        b2 = fmaf(cA2, bflo(u2.y), b2); b3 = fmaf(cA2, bfhi(u2.y), b3);
        b0 = fmaf(cA3, bflo(u3.x), b0); b1 = fmaf(cA3, bfhi(u3.x), b1);
        b2 = fmaf(cA3, bflo(u3.y), b2); b3 = fmaf(cA3, bfhi(u3.y), b3);
        b0 = fmaf(cA4, bflo(pu.x), b0); b1 = fmaf(cA4, bfhi(pu.x), b1);
        b2 = fmaf(cA4, bflo(pu.y), b2); b3 = fmaf(cA4, bfhi(pu.y), b3);
        b0 = fmaf(cA5, bflo(u5.x), b0); b1 = fmaf(cA5, bfhi(u5.x), b1);
        b2 = fmaf(cA5, bflo(u5.y), b2); b3 = fmaf(cA5, bfhi(u5.y), b3);
        b0 = fmaf(cA6, s0v, b0); b1 = fmaf(cA6, s1v, b1);
        b2 = fmaf(cA6, s2v, b2); b3 = fmaf(cA6, s3v, b3);
        float rd = rdinv[r];
        b0 *= rd; b1 *= rd; b2 *= rd; b3 *= rd;
        float4* op = (float4*)outacc + di2;
        if (MODE == 2) {
            *op = make_float4(b0, b1, b2, b3);
        } else {
            float4 pv = *op;
            int f0 = fl * 4;
            float v0 = pv.x + b0 + bias[f0];
            float v1 = pv.y + b1 + bias[f0 + 1];
            float v2 = pv.z + b2 + bias[f0 + 2];
            float v3 = pv.w + b3 + bias[f0 + 3];
            *op = make_float4(v0 > 0.f ? v0 : 0.f, v1 > 0.f ? v1 : 0.f,
                              v2 > 0.f ? v2 : 0.f, v3 > 0.f ? v3 : 0.f);
        }
    }
}

// run-length compressed segment sum over sorted batch; wave = 32 nodes, lane = feature
__global__ void k_pool(const float* __restrict__ h, const int* __restrict__ batch,
                       float* __restrict__ sums, float* __restrict__ cntf, int n) {
    int wid = (blockIdx.x * blockDim.x + threadIdx.x) >> 6;
    int lane = threadIdx.x & 63;
    int start = wid * 32;
    if (start >= n) return;
    int end = start + 32;
    if (end > n) end = n;
    float acc = 0.f;
    int run = 0;
    int g = batch[start];
    for (int i = start; i < end; ++i) {
        int gi = batch[i];
        if (gi != g) {
            atomicAdd(&sums[g * 64 + lane], acc);
            if (lane == 0) atomicAdd(&cntf[g], (float)run);
            acc = 0.f;
            run = 0;
            g = gi;
        }
        acc += h[(size_t)i * 64 + lane];
        run++;
    }
    atomicAdd(&sums[g * 64 + lane], acc);
    if (lane == 0) atomicAdd(&cntf[g], (float)run);
}

// per-graph head: pooled = sums/cnt ; g = relu(pooled@w1+b1) ; logits = g@w2+b2 ; log_softmax
__global__ void k_head(const float* __restrict__ sums, const float* __restrict__ cntf,
                       const float* __restrict__ w1, const float* __restrict__ b1,
                       const float* __restrict__ w2, const float* __restrict__ b2,
                       float* __restrict__ out) {
    __shared__ float pl[64], gl[64], lg[NCLASSES];
    int g = blockIdx.x, t = threadIdx.x;
    float c = cntf[g];
    if (c < 1.f) c = 1.f;
    pl[t] = sums[g * 64 + t] / c;
    __syncthreads();
    float a = b1[t];
    for (int f = 0; f < 64; ++f) a += pl[f] * w1[f * 64 + t];
    gl[t] = a > 0.f ? a : 0.f;
    __syncthreads();
    if (t < NCLASSES) {
        float a2 = b2[t];
        for (int f = 0; f < 64; ++f) a2 += gl[f] * w2[f * NCLASSES + t];
        lg[t] = a2;
    }
    __syncthreads();
    if (t < NCLASSES) {
        float m = lg[0];
        for (int i = 1; i < NCLASSES; ++i) m = fmaxf(m, lg[i]);
        float s = 0.f;
        for (int i = 0; i < NCLASSES; ++i) s += expf(lg[i] - m);
        out[g * NCLASSES + t] = lg[t] - m - logf(s);
    }
}

// ---------------- host ----------------

extern "C" void kernel_launch(void* const* d_in, const int* in_sizes, int n_in,
                              void* d_out, int out_size, void* d_ws, size_t ws_size,
                              hipStream_t stream) {
    const float* x   = (const float*)d_in[0];
    const int*   ei  = (const int*)d_in[1];
    const int*   bat = (const int*)d_in[2];
    const float* W1  = (const float*)d_in[3];
    const float* th1 = (const float*)d_in[4];
    const float* b1  = (const float*)d_in[5];
    const float* Ws  = (const float*)d_in[6];
    const float* ths = (const float*)d_in[7];
    const float* bs  = (const float*)d_in[8];
    const float* l1w = (const float*)d_in[9];
    const float* l1b = (const float*)d_in[10];
    const float* l2w = (const float*)d_in[11];
    const float* l2b = (const float*)d_in[12];
    float* out = (float*)d_out;

    const int n  = in_sizes[2];
    const int ne = in_sizes[1] / 2;
    const int* erow = ei;
    const int* ecol = ei + ne;

    // workspace carve
    char* w = (char*)d_ws;
    size_t off = 0;
    auto carve = [&](size_t bytes) {
        void* p = w + off;
        off += align256(bytes);
        return p;
    };
    const size_t ne_pad = (size_t)ne + 7 * (size_t)n + 8;
    const size_t slabd = (size_t)(n + 1) * 32;
    int*   deg    = (int*)carve((size_t)n * 4);
    int*   rowptr = (int*)carve((size_t)(n + 1) * 4);
    int*   cursor = (int*)carve((size_t)n * 4);
    int*   bsum   = (int*)carve(1024 * 4);
    int*   ccol   = (int*)carve(ne_pad * 4);
    float* dinv   = (float*)carve((size_t)n * 4);
    float* d2     = (float*)carve((size_t)n * 4);
    float* rdinv  = (float*)carve((size_t)n * 4);
    float* coeff  = (float*)carve(3 * KORD * 4);
    float* sums   = (float*)carve((size_t)NGRAPHS * 64 * 4);
    float* cntf   = (float*)carve((size_t)NGRAPHS * 4);
    float* outacc = (float*)carve((size_t)n * 64 * 4);  // doubles as H
    unsigned* slabs = (unsigned*)carve(7 * slabd * 4);
    auto slab = [&](int s) { return slabs + (size_t)s * slabd; };
    (void)ws_size; (void)n_in; (void)out_size;

    const int nb256e = (ne + 255) / 256;
    const int nb256n = (n + 255) / 256;

    hipMemsetAsync(deg, 0, (size_t)n * 4, stream);
    hipMemsetAsync(sums, 0, (size_t)NGRAPHS * 64 * 4, stream);
    hipMemsetAsync(cntf, 0, (size_t)NGRAPHS * 4, stream);

    k_deg<<<nb256e, 256, 0, stream>>>(erow, deg, ne);
    k_dinv<<<nb256n, 256, 0, stream>>>(deg, dinv, d2, rdinv, n);
    k_scan1<<<nb256n, 256, 0, stream>>>(deg, rowptr, bsum, n);
    k_scan2<<<1, 1024, 0, stream>>>(bsum, nb256n);
    k_scan3<<<nb256n, 256, 0, stream>>>(rowptr, cursor, bsum, deg, n);
    k_filln<<<(int)((ne_pad + 255) / 256), 256, 0, stream>>>(ccol, (int)ne_pad, n);
    k_fill<<<nb256e, 256, 0, stream>>>(erow, ecol, cursor, ccol, ne);
    k_zrow<<<1, 256, 0, stream>>>(slabs, n);
    k_coeff<<<1, 64, 0, stream>>>(th1, ths, coeff);

    const int pb = (n + 3) / 4;  // 4 waves (rows) per 256-thread block

    for (int l = 0; l < 3; ++l) {
        const float* cf = coeff + l * KORD;
        const float* bias = (l == 0) ? b1 : bs + (l - 1) * HID;

        if (l == 0)
            k_gemm<FIN><<<(n + 63) / 64, 256, 0, stream>>>(x, W1, slab(0), dinv, n);
        else
            k_gemm<HID><<<(n + 63) / 64, 256, 0, stream>>>(outacc, Ws + (size_t)(l - 1) * HID * HID,
                                                           slab(0), dinv, n);

        // k=1: S1 = L~_S S0
        k_prop<0><<<pb, 256, 0, stream>>>(rowptr, ccol, slab(0), nullptr, slab(1), d2,
                                          nullptr, nullptr, nullptr, nullptr, nullptr,
                                          nullptr, nullptr, nullptr, nullptr, n);
        // k=2..5
        for (int k = 2; k <= 5; ++k)
            k_prop<1><<<pb, 256, 0, stream>>>(rowptr, ccol, slab(k - 1), slab(k - 2), slab(k), d2,
                                              nullptr, nullptr, nullptr, nullptr, nullptr,
                                              nullptr, nullptr, nullptr, nullptr, n);
        // k=6 + fused acc of S0..S6
        k_prop<2><<<pb, 256, 0, stream>>>(rowptr, ccol, slab(5), slab(4), slab(6), d2,
                                          slab(0), slab(1), slab(2), slab(3), slab(5),
                                          cf, rdinv, nullptr, outacc, n);
        // k=7..12 (slab k%7)
        for (int k = 7; k <= 12; ++k)
            k_prop<1><<<pb, 256, 0, stream>>>(rowptr, ccol, slab((k - 1) % 7), slab((k - 2) % 7),
                                              slab(k % 7), d2,
                                              nullptr, nullptr, nullptr, nullptr, nullptr,
                                              nullptr, nullptr, nullptr, nullptr, n);
        // k=13 + fused final acc of S7..S13, bias, relu -> H
        k_prop<3><<<pb, 256, 0, stream>>>(rowptr, ccol, slab(5), slab(4), slab(6), d2,
                                          slab(0), slab(1), slab(2), slab(3), slab(5),
                                          cf + 7, rdinv, bias, outacc, n);
    }

    const int poolwaves = (n + 31) / 32;
    const int poolblocks = (poolwaves * 64 + 255) / 256;
    k_pool<<<poolblocks, 256, 0, stream>>>(outacc, bat, sums, cntf, n);
    k_head<<<NGRAPHS, 64, 0, stream>>>(sums, cntf, l1w, l1b, l2w, l2b, out);
}